// Round 10
// baseline (393.303 us; speedup 1.0000x reference)
//
#include <hip/hip_runtime.h>
#include <hip/hip_fp16.h>
#include <math.h>

// ---------------------------------------------------------------------------
// GAT graph encoder: 2x GATConv (PyG semantics, add_self_loops=False)
// R13->R14: k_agg epilogue wave-parallelized. Previously 16 lanes (g==0)
//   finalized 8 cols each (~110 issued instr/node, 48 lanes idle). Now all
//   64 lanes finalize 2 cols (sub*8+2g) after the butterfly (which already
//   leaves full sums in every lane): ~25 instr/node. o[2g] selected via
//   unrolled compare chain (no runtime reg-array indexing -> no scratch).
//   Store __half2/float2 per lane (same 256B/node). Remainder noise ~±12us
//   observed across R11/R12/R13 (identical code, 25us spread) -> GEMM kept
//   as R12 form, no remainder claims this round.
// ---------------------------------------------------------------------------

typedef _Float16 f16x8 __attribute__((ext_vector_type(8)));
typedef float    f32x4 __attribute__((ext_vector_type(4)));

// ---------------- CSR build ----------------

__global__ __launch_bounds__(256) void k_hist(const int* __restrict__ dst,
                                              int* __restrict__ bcnt, int E, int NBUCK) {
    __shared__ int lh[1024];
    int t = threadIdx.x;
    for (int i = t; i < NBUCK; i += 256) lh[i] = 0;
    __syncthreads();
    for (int e = blockIdx.x * 256 + t; e < E; e += gridDim.x * 256)
        atomicAdd(&lh[dst[e] >> 7], 1);
    __syncthreads();
    for (int i = t; i < NBUCK; i += 256) {
        int c = lh[i];
        if (c) atomicAdd(&bcnt[i], c);
    }
}

__global__ void k_bscan(const int* __restrict__ bcnt, int* __restrict__ bbase,
                        int* __restrict__ bcur, int* __restrict__ off,
                        int NBUCK, int N, int E) {
    __shared__ int sd[1024];
    int t = threadIdx.x;
    int v = (t < NBUCK) ? bcnt[t] : 0;
    sd[t] = v; __syncthreads();
    for (int ofs = 1; ofs < 1024; ofs <<= 1) {
        int w = (t >= ofs) ? sd[t - ofs] : 0;
        __syncthreads();
        sd[t] += w;
        __syncthreads();
    }
    if (t < NBUCK) { int ex = sd[t] - v; bbase[t] = ex; bcur[t] = ex; }
    if (t == 0) { bbase[NBUCK] = E; off[N] = E; }
}

__global__ __launch_bounds__(256) void k_binscatter(
    const int* __restrict__ src, const int* __restrict__ dst,
    int* __restrict__ bcur, int* __restrict__ tmp, int E, int NBUCK) {
    __shared__ int lh[1024], lbase[1024];
    int t = threadIdx.x;
    for (int i = t; i < NBUCK; i += 256) lh[i] = 0;
    __syncthreads();
    int tbeg = blockIdx.x * 8192;
    int tend = tbeg + 8192; if (tend > E) tend = E;
    for (int e = tbeg + t; e < tend; e += 256) atomicAdd(&lh[dst[e] >> 7], 1);
    __syncthreads();
    for (int i = t; i < NBUCK; i += 256) {
        int c = lh[i];
        lbase[i] = c ? atomicAdd(&bcur[i], c) : 0;
        lh[i] = 0;
    }
    __syncthreads();
    for (int e = tbeg + t; e < tend; e += 256) {
        int d = dst[e];
        int b = d >> 7;
        int r = atomicAdd(&lh[b], 1);
        tmp[lbase[b] + r] = (src[e] << 7) | (d & 127);
    }
}

__global__ __launch_bounds__(256) void k_bsort(
    const int* __restrict__ tmp, const int* __restrict__ bbase,
    int* __restrict__ off, int* __restrict__ esrc, int N) {
    __shared__ int h[128], hs[128], cur[128];
    int b = blockIdx.x, t = threadIdx.x;
    int base = bbase[b];
    int cnt  = bbase[b + 1] - base;
    int node0 = b << 7;
    if (t < 128) h[t] = 0;
    __syncthreads();
    for (int i = t; i < cnt; i += 256) atomicAdd(&h[tmp[base + i] & 127], 1);
    __syncthreads();
    if (t < 128) hs[t] = h[t];
    __syncthreads();
    for (int ofs = 1; ofs < 128; ofs <<= 1) {
        int w = (t < 128 && t >= ofs) ? hs[t - ofs] : 0;
        __syncthreads();
        if (t < 128) hs[t] += w;
        __syncthreads();
    }
    if (t < 128) {
        int ex = hs[t] - h[t];
        if (node0 + t < N) off[node0 + t] = base + ex;
        cur[t] = base + ex;
    }
    __syncthreads();
    for (int i = t; i < cnt; i += 256) {
        int p = tmp[base + i];
        int pos = atomicAdd(&cur[p & 127], 1);
        esrc[pos] = p >> 7;
    }
}

// ---------------- MFMA GEMM + fused attention dots ----------------
// Y(fp16)[N,128] = cast16(X[N,128]) @ cast16(W[128,128]); fp32 accum.
// A-frag: m=lane&15 (row), k=(lane>>4)*8+j. B-frag: n=lane&15 (col), same k.
// C/D: col=lane&15, row=(lane>>4)*4+reg.
// R12 form: W in LDS fragment-major; streamed B-frags; 3 blocks/CU.

template <int H, typename TI>
__global__ __launch_bounds__(256, 3) void k_gemm_mfma(
    const TI* __restrict__ X, const float* __restrict__ Wg,
    const float* __restrict__ att_s, const float* __restrict__ att_d,
    __half* __restrict__ Y, float* __restrict__ as_, float* __restrict__ ad_, int N)
{
    __shared__ _Float16 Wf[8][4][512];   // [nt][ks][lane*8+j], 32 KB
    __shared__ _Float16 Xh[64][136];     // +8 pad: breaks 256B-stride bank clash
    const int t = threadIdx.x;
    const int lane = t & 63;
    const int wv = t >> 6;
    const int m = lane & 15;
    const int q = lane >> 4;

    // stage W fp32 -> fp16 fragment-major: 2048 fragments, 8 per thread.
    for (int f = t; f < 2048; f += 256) {
        int nt = f >> 8, ks = (f >> 6) & 3, ls = f & 63;
        int qq = ls >> 4, mm = ls & 15;
        int col = nt * 16 + mm;
        int k0  = ks * 32 + qq * 8;
        f16x8 frag;
#pragma unroll
        for (int j = 0; j < 8; j++)
            frag[j] = (_Float16)Wg[(size_t)(k0 + j) * 128 + col];
        *(f16x8*)&Wf[nt][ks][ls * 8] = frag;
    }

    float atts_v[8], attd_v[8];
#pragma unroll
    for (int nt = 0; nt < 8; nt++) {
        atts_v[nt] = att_s[nt * 16 + m];
        attd_v[nt] = att_d[nt * 16 + m];
    }
    __syncthreads();

    for (int base = blockIdx.x * 64; base < N; base += gridDim.x * 64) {
        // stage 64 rows of X -> fp16 LDS (1024 chunks of 8 halfs, 4/thread)
        for (int i = t; i < 1024; i += 256) {
            int r = i >> 4, c8 = i & 15;
            int gr = base + r;
            _Float16* d = &Xh[r][c8 * 8];
            if (gr < N) {
                if constexpr (sizeof(TI) == 4) {
                    const float4* s = (const float4*)((const float*)X + (size_t)gr * 128 + c8 * 8);
                    float4 x0 = s[0], x1 = s[1];
                    d[0] = (_Float16)x0.x; d[1] = (_Float16)x0.y;
                    d[2] = (_Float16)x0.z; d[3] = (_Float16)x0.w;
                    d[4] = (_Float16)x1.x; d[5] = (_Float16)x1.y;
                    d[6] = (_Float16)x1.z; d[7] = (_Float16)x1.w;
                } else {
                    *(uint4*)d = *(const uint4*)((const __half*)X + (size_t)gr * 128 + c8 * 8);
                }
            } else {
                uint4 z; z.x = 0; z.y = 0; z.z = 0; z.w = 0;
                *(uint4*)d = z;
            }
        }
        __syncthreads();

        const int rowb = base + wv * 16;

        // A-fragments for this wave's 16 rows (4 x ds_read_b128)
        f16x8 af[4];
#pragma unroll
        for (int ks = 0; ks < 4; ks++)
            af[ks] = *(const f16x8*)&Xh[wv * 16 + m][ks * 32 + q * 8];

        f32x4 acc[8];
#pragma unroll
        for (int nt = 0; nt < 8; nt++) { acc[nt][0] = 0.f; acc[nt][1] = 0.f; acc[nt][2] = 0.f; acc[nt][3] = 0.f; }

        // stream B-fragments from LDS per nt (4 x ds_read_b128 + 4 MFMA)
#pragma unroll
        for (int nt = 0; nt < 8; nt++) {
            f16x8 b0v = *(const f16x8*)&Wf[nt][0][lane * 8];
            f16x8 b1v = *(const f16x8*)&Wf[nt][1][lane * 8];
            f16x8 b2v = *(const f16x8*)&Wf[nt][2][lane * 8];
            f16x8 b3v = *(const f16x8*)&Wf[nt][3][lane * 8];
            acc[nt] = __builtin_amdgcn_mfma_f32_16x16x32_f16(af[0], b0v, acc[nt], 0, 0, 0);
            acc[nt] = __builtin_amdgcn_mfma_f32_16x16x32_f16(af[1], b1v, acc[nt], 0, 0, 0);
            acc[nt] = __builtin_amdgcn_mfma_f32_16x16x32_f16(af[2], b2v, acc[nt], 0, 0, 0);
            acc[nt] = __builtin_amdgcn_mfma_f32_16x16x32_f16(af[3], b3v, acc[nt], 0, 0, 0);
        }

        // Y writes (fp16 scalar stores; C-layout)
#pragma unroll
        for (int nt = 0; nt < 8; nt++) {
#pragma unroll
            for (int i = 0; i < 4; i++) {
                int r = rowb + q * 4 + i;
                if (r < N) Y[(size_t)r * 128 + nt * 16 + m] = __float2half(acc[nt][i]);
            }
        }

        // fused attention dots: per-lane partials, butterfly over the 16 cols
        if (H == 4) {
            float ph[4][4], pdv[4][4];
#pragma unroll
            for (int h = 0; h < 4; h++)
#pragma unroll
                for (int i = 0; i < 4; i++) {
                    ph[h][i]  = acc[2 * h][i] * atts_v[2 * h] + acc[2 * h + 1][i] * atts_v[2 * h + 1];
                    pdv[h][i] = acc[2 * h][i] * attd_v[2 * h] + acc[2 * h + 1][i] * attd_v[2 * h + 1];
                }
#pragma unroll
            for (int lvl = 0; lvl < 4; lvl++) {
                const int msk = 1 << lvl;
#pragma unroll
                for (int h = 0; h < 4; h++)
#pragma unroll
                    for (int i = 0; i < 4; i++) {
                        ph[h][i]  += __shfl_xor(ph[h][i], msk, 64);
                        pdv[h][i] += __shfl_xor(pdv[h][i], msk, 64);
                    }
            }
            if (m == 0) {
#pragma unroll
                for (int i = 0; i < 4; i++) {
                    int r = rowb + q * 4 + i;
                    if (r < N) {
#pragma unroll
                        for (int h = 0; h < 4; h++) {
                            as_[(size_t)r * 4 + h] = ph[h][i];
                            ad_[(size_t)r * 4 + h] = pdv[h][i];
                        }
                    }
                }
            }
        } else {
            float ps[4], pdv[4];
#pragma unroll
            for (int i = 0; i < 4; i++) {
                float s = 0.f, dsum = 0.f;
#pragma unroll
                for (int nt = 0; nt < 8; nt++) {
                    s    += acc[nt][i] * atts_v[nt];
                    dsum += acc[nt][i] * attd_v[nt];
                }
                ps[i] = s; pdv[i] = dsum;
            }
#pragma unroll
            for (int lvl = 0; lvl < 4; lvl++) {
                const int msk = 1 << lvl;
#pragma unroll
                for (int i = 0; i < 4; i++) {
                    ps[i]  += __shfl_xor(ps[i], msk, 64);
                    pdv[i] += __shfl_xor(pdv[i], msk, 64);
                }
            }
            if (m == 0) {
#pragma unroll
                for (int i = 0; i < 4; i++) {
                    int r = rowb + q * 4 + i;
                    if (r < N) { as_[r] = ps[i]; ad_[r] = pdv[i]; }
                }
            }
        }
        __syncthreads();   // protect Xh before next tile's staging
    }
}

// ---------------- aggregation: one wave per dst node ----------------
// R11 gather core (measured 70.9-71.1us, stable): 16 lanes per edge at
// 16B/lane; batches of 16 edges, 4 uint4 loads issued before consumption;
// tail predicated by zero weight.
// R14 epilogue: wave-parallel. After the xor-16/32 butterfly ALL lanes hold
// the reduced sums; each lane finalizes 2 cols (sub*8+2g) -> half2/float2
// store. o[2g] picked via unrolled compare chain (no scratch).

template <int H, typename TO>
__global__ __launch_bounds__(256) void k_agg(
    const __half* __restrict__ feat,  // [N,128] fp16
    const float* __restrict__ asrc,   // [N,H]
    const float* __restrict__ adst,   // [N,H]
    const int*   __restrict__ off,    // [N+1]
    const int*   __restrict__ esrc,   // [E]
    const float* __restrict__ bias,   // [128]
    TO*          __restrict__ out,    // [N,128]
    int N)
{
    __shared__ __attribute__((aligned(16))) int   sj[4][64];
    __shared__ __attribute__((aligned(16))) float sp[4][64 * H];  // head-major

    int wave = threadIdx.x >> 6;
    int lane = threadIdx.x & 63;
    int node = (blockIdx.x * 256 + threadIdx.x) >> 6;
    if (node >= N) return;
    int beg = off[node], end = off[node + 1];

    float adst_i[H];
#pragma unroll
    for (int h = 0; h < H; h++) adst_i[h] = adst[(size_t)node * H + h];

    const int g    = lane >> 4;                    // edge sub-slot 0..3
    const int sub  = lane & 15;                    // col octet: cols sub*8..+7
    const int head = (H == 4) ? (sub >> 2) : 0;    // 32 cols per head
    const __half* fb = feat + sub * 8;

    float o[8];
#pragma unroll
    for (int k = 0; k < 8; k++) o[k] = 0.f;
    float ssum = 0.f;

    for (int cbeg = beg; cbeg < end; cbeg += 64) {
        int cnt = end - cbeg; if (cnt > 64) cnt = 64;
        if (lane < cnt) {
            int j = esrc[cbeg + lane];
            sj[wave][lane] = j;
            if (H == 4) {
                float4 av = *(const float4*)(asrc + (size_t)j * 4);
                float e;
                e = av.x + adst_i[0]; e = e > 0.f ? e : 0.2f * e; sp[wave][0 * 64 + lane] = __expf(e);
                e = av.y + adst_i[1]; e = e > 0.f ? e : 0.2f * e; sp[wave][1 * 64 + lane] = __expf(e);
                e = av.z + adst_i[2]; e = e > 0.f ? e : 0.2f * e; sp[wave][2 * 64 + lane] = __expf(e);
                e = av.w + adst_i[3]; e = e > 0.f ? e : 0.2f * e; sp[wave][3 * 64 + lane] = __expf(e);
            } else {
                float e = asrc[j] + adst_i[0];
                e = e > 0.f ? e : 0.2f * e;
                sp[wave][lane] = __expf(e);
            }
        }
        asm volatile("s_waitcnt lgkmcnt(0)" ::: "memory");

        // batches of 16 edges: issue 4 gathers back-to-back, then consume.
        for (int b0 = 0; b0 < cnt; b0 += 16) {
            float aa[4]; uint4 hv[4];
#pragma unroll
            for (int u = 0; u < 4; u++) {
                int e  = b0 + 4 * u + g;
                bool ok = e < cnt;
                int ec = ok ? e : 0;
                int j  = sj[wave][ec];
                aa[u]  = ok ? sp[wave][head * 64 + ec] : 0.f;
                hv[u]  = *(const uint4*)(fb + (size_t)j * 128);
            }
#pragma unroll
            for (int u = 0; u < 4; u++) {
                const __half* hp = (const __half*)&hv[u];
                ssum += aa[u];
#pragma unroll
                for (int k = 0; k < 8; k++)
                    o[k] = fmaf(aa[u], __half2float(hp[k]), o[k]);
            }
        }
        // same-wave lockstep: staging of the next chunk cannot race these reads
    }

    // reduce across the 4 edge-groups: butterfly leaves full sums in ALL lanes
#pragma unroll
    for (int k = 0; k < 8; k++) {
        o[k] += __shfl_xor(o[k], 16, 64);
        o[k] += __shfl_xor(o[k], 32, 64);
    }
    ssum += __shfl_xor(ssum, 16, 64);
    ssum += __shfl_xor(ssum, 32, 64);

    // wave-parallel epilogue: each lane finalizes 2 cols (sub*8 + 2g)
    float so0 = o[0], so1 = o[1];
    if (g == 1) { so0 = o[2]; so1 = o[3]; }
    if (g == 2) { so0 = o[4]; so1 = o[5]; }
    if (g == 3) { so0 = o[6]; so1 = o[7]; }

    const int c2 = sub * 8 + 2 * g;
    float inv = 1.f / (ssum + 1e-16f);
    float r0 = so0 * inv + bias[c2];
    float r1 = so1 * inv + bias[c2 + 1];
    float e0 = __expf(r0) - 1.0f;                  // cheap ELU (abs err ~1e-6)
    float e1 = __expf(r1) - 1.0f;
    r0 = r0 > 0.f ? r0 : e0;
    r1 = r1 > 0.f ? r1 : e1;

    if constexpr (sizeof(TO) == 2) {
        *(__half2*)((__half*)out + (size_t)node * 128 + c2) = __floats2half2_rn(r0, r1);
    } else {
        *(float2*)((float*)out + (size_t)node * 128 + c2) = make_float2(r0, r1);
    }
}

// ---------------- launch ----------------

extern "C" void kernel_launch(void* const* d_in, const int* in_sizes, int n_in,
                              void* d_out, int out_size, void* d_ws, size_t ws_size,
                              hipStream_t stream)
{
    const float* x    = (const float*)d_in[0];
    const int*   a    = (const int*)  d_in[1];
    const float* W1   = (const float*)d_in[2];
    const float* as1w = (const float*)d_in[3];
    const float* ad1w = (const float*)d_in[4];
    const float* b1   = (const float*)d_in[5];
    const float* W2   = (const float*)d_in[6];
    const float* as2w = (const float*)d_in[7];
    const float* ad2w = (const float*)d_in[8];
    const float* b2   = (const float*)d_in[9];

    const int N = in_sizes[0] / 128;
    const int E = in_sizes[1] / 2;
    const int* srcA = a;
    const int* dstA = a + E;
    const int NBUCK = (N + 127) >> 7;

    char* ws = (char*)d_ws;
    size_t o = 0;
    auto alloc = [&](size_t bytes) -> void* {
        void* p = ws + o;
        o += (bytes + 255) & ~(size_t)255;
        return p;
    };
    __half* hbuf  = (__half*)alloc((size_t)N * 128 * 2);  // fp16 gather payload
    __half* hact  = (__half*)alloc((size_t)N * 128 * 2);  // elu(gat1) fp16, GEMM2 input
    float*  as1   = (float*) alloc((size_t)N * 4 * 4);
    float*  ad1   = (float*) alloc((size_t)N * 4 * 4);
    float*  as2   = (float*) alloc((size_t)N * 4);
    float*  ad2   = (float*) alloc((size_t)N * 4);
    int*    off   = (int*)   alloc((size_t)(N + 1) * 4);
    int*    esrc  = (int*)   alloc((size_t)E * 4);
    int*    tmp   = (int*)   alloc((size_t)E * 4);
    int*    bcnt  = (int*)   alloc(1024 * 4);
    int*    bbase = (int*)   alloc(1025 * 4);
    int*    bcur  = (int*)   alloc(1024 * 4);

    // CSR build (rebuilt each launch; ws is re-poisoned)
    hipMemsetAsync(bcnt, 0, (size_t)NBUCK * 4, stream);
    k_hist<<<256, 256, 0, stream>>>(dstA, bcnt, E, NBUCK);
    k_bscan<<<1, 1024, 0, stream>>>(bcnt, bbase, bcur, off, NBUCK, N, E);
    k_binscatter<<<(E + 8191) / 8192, 256, 0, stream>>>(srcA, dstA, bcur, tmp, E, NBUCK);
    k_bsort<<<NBUCK, 256, 0, stream>>>(tmp, bbase, off, esrc, N);

    // layer 1 (MFMA GEMM + fused attdot, fp16 Y)
    k_gemm_mfma<4, float><<<768, 256, 0, stream>>>(x, W1, as1w, ad1w, hbuf, as1, ad1, N);
    k_agg<4, __half><<<(N + 3) / 4, 256, 0, stream>>>(hbuf, as1, ad1, off, esrc, b1, hact, N);

    // layer 2
    k_gemm_mfma<1, __half><<<768, 256, 0, stream>>>(hact, W2, as2w, ad2w, hbuf, as2, ad2, N);
    k_agg<1, float><<<(N + 3) / 4, 256, 0, stream>>>(hbuf, as2, ad2, off, esrc, b2, (float*)d_out, N);
}

// Round 11
// 340.595 us; speedup vs baseline: 1.1548x; 1.1548x over previous
//
#include <hip/hip_runtime.h>
#include <hip/hip_fp16.h>
#include <math.h>

// ---------------------------------------------------------------------------
// GAT graph encoder: 2x GATConv (PyG semantics, add_self_loops=False)
// R14->R15: R14's regression root-caused via counters: conditional
//   cross-element reads of float o[8] defeated SROA -> alloca ->
//   AMDGPUPromoteAlloca placed it in LDS (+8192B = 256thr x 32B exactly;
//   bank conflicts 2.47M->6.87M, k_agg 70.9->80.4us). Fix: accumulator as 8
//   NAMED SCALARS o0..o7 (no array object); g-selection via cndmask chains
//   on SSA values. Wave-parallel epilogue retained (all 64 lanes finalize
//   2 cols each). Everything else byte-identical to R13.
// ---------------------------------------------------------------------------

typedef _Float16 f16x8 __attribute__((ext_vector_type(8)));
typedef float    f32x4 __attribute__((ext_vector_type(4)));

// ---------------- CSR build ----------------

__global__ __launch_bounds__(256) void k_hist(const int* __restrict__ dst,
                                              int* __restrict__ bcnt, int E, int NBUCK) {
    __shared__ int lh[1024];
    int t = threadIdx.x;
    for (int i = t; i < NBUCK; i += 256) lh[i] = 0;
    __syncthreads();
    for (int e = blockIdx.x * 256 + t; e < E; e += gridDim.x * 256)
        atomicAdd(&lh[dst[e] >> 7], 1);
    __syncthreads();
    for (int i = t; i < NBUCK; i += 256) {
        int c = lh[i];
        if (c) atomicAdd(&bcnt[i], c);
    }
}

__global__ void k_bscan(const int* __restrict__ bcnt, int* __restrict__ bbase,
                        int* __restrict__ bcur, int* __restrict__ off,
                        int NBUCK, int N, int E) {
    __shared__ int sd[1024];
    int t = threadIdx.x;
    int v = (t < NBUCK) ? bcnt[t] : 0;
    sd[t] = v; __syncthreads();
    for (int ofs = 1; ofs < 1024; ofs <<= 1) {
        int w = (t >= ofs) ? sd[t - ofs] : 0;
        __syncthreads();
        sd[t] += w;
        __syncthreads();
    }
    if (t < NBUCK) { int ex = sd[t] - v; bbase[t] = ex; bcur[t] = ex; }
    if (t == 0) { bbase[NBUCK] = E; off[N] = E; }
}

__global__ __launch_bounds__(256) void k_binscatter(
    const int* __restrict__ src, const int* __restrict__ dst,
    int* __restrict__ bcur, int* __restrict__ tmp, int E, int NBUCK) {
    __shared__ int lh[1024], lbase[1024];
    int t = threadIdx.x;
    for (int i = t; i < NBUCK; i += 256) lh[i] = 0;
    __syncthreads();
    int tbeg = blockIdx.x * 8192;
    int tend = tbeg + 8192; if (tend > E) tend = E;
    for (int e = tbeg + t; e < tend; e += 256) atomicAdd(&lh[dst[e] >> 7], 1);
    __syncthreads();
    for (int i = t; i < NBUCK; i += 256) {
        int c = lh[i];
        lbase[i] = c ? atomicAdd(&bcur[i], c) : 0;
        lh[i] = 0;
    }
    __syncthreads();
    for (int e = tbeg + t; e < tend; e += 256) {
        int d = dst[e];
        int b = d >> 7;
        int r = atomicAdd(&lh[b], 1);
        tmp[lbase[b] + r] = (src[e] << 7) | (d & 127);
    }
}

__global__ __launch_bounds__(256) void k_bsort(
    const int* __restrict__ tmp, const int* __restrict__ bbase,
    int* __restrict__ off, int* __restrict__ esrc, int N) {
    __shared__ int h[128], hs[128], cur[128];
    int b = blockIdx.x, t = threadIdx.x;
    int base = bbase[b];
    int cnt  = bbase[b + 1] - base;
    int node0 = b << 7;
    if (t < 128) h[t] = 0;
    __syncthreads();
    for (int i = t; i < cnt; i += 256) atomicAdd(&h[tmp[base + i] & 127], 1);
    __syncthreads();
    if (t < 128) hs[t] = h[t];
    __syncthreads();
    for (int ofs = 1; ofs < 128; ofs <<= 1) {
        int w = (t < 128 && t >= ofs) ? hs[t - ofs] : 0;
        __syncthreads();
        if (t < 128) hs[t] += w;
        __syncthreads();
    }
    if (t < 128) {
        int ex = hs[t] - h[t];
        if (node0 + t < N) off[node0 + t] = base + ex;
        cur[t] = base + ex;
    }
    __syncthreads();
    for (int i = t; i < cnt; i += 256) {
        int p = tmp[base + i];
        int pos = atomicAdd(&cur[p & 127], 1);
        esrc[pos] = p >> 7;
    }
}

// ---------------- MFMA GEMM + fused attention dots ----------------
// Y(fp16)[N,128] = cast16(X[N,128]) @ cast16(W[128,128]); fp32 accum.
// A-frag: m=lane&15 (row), k=(lane>>4)*8+j. B-frag: n=lane&15 (col), same k.
// C/D: col=lane&15, row=(lane>>4)*4+reg.
// R12 form: W in LDS fragment-major; streamed B-frags; 3 blocks/CU.

template <int H, typename TI>
__global__ __launch_bounds__(256, 3) void k_gemm_mfma(
    const TI* __restrict__ X, const float* __restrict__ Wg,
    const float* __restrict__ att_s, const float* __restrict__ att_d,
    __half* __restrict__ Y, float* __restrict__ as_, float* __restrict__ ad_, int N)
{
    __shared__ _Float16 Wf[8][4][512];   // [nt][ks][lane*8+j], 32 KB
    __shared__ _Float16 Xh[64][136];     // +8 pad: breaks 256B-stride bank clash
    const int t = threadIdx.x;
    const int lane = t & 63;
    const int wv = t >> 6;
    const int m = lane & 15;
    const int q = lane >> 4;

    // stage W fp32 -> fp16 fragment-major: 2048 fragments, 8 per thread.
    for (int f = t; f < 2048; f += 256) {
        int nt = f >> 8, ks = (f >> 6) & 3, ls = f & 63;
        int qq = ls >> 4, mm = ls & 15;
        int col = nt * 16 + mm;
        int k0  = ks * 32 + qq * 8;
        f16x8 frag;
#pragma unroll
        for (int j = 0; j < 8; j++)
            frag[j] = (_Float16)Wg[(size_t)(k0 + j) * 128 + col];
        *(f16x8*)&Wf[nt][ks][ls * 8] = frag;
    }

    float atts_v[8], attd_v[8];
#pragma unroll
    for (int nt = 0; nt < 8; nt++) {
        atts_v[nt] = att_s[nt * 16 + m];
        attd_v[nt] = att_d[nt * 16 + m];
    }
    __syncthreads();

    for (int base = blockIdx.x * 64; base < N; base += gridDim.x * 64) {
        // stage 64 rows of X -> fp16 LDS (1024 chunks of 8 halfs, 4/thread)
        for (int i = t; i < 1024; i += 256) {
            int r = i >> 4, c8 = i & 15;
            int gr = base + r;
            _Float16* d = &Xh[r][c8 * 8];
            if (gr < N) {
                if constexpr (sizeof(TI) == 4) {
                    const float4* s = (const float4*)((const float*)X + (size_t)gr * 128 + c8 * 8);
                    float4 x0 = s[0], x1 = s[1];
                    d[0] = (_Float16)x0.x; d[1] = (_Float16)x0.y;
                    d[2] = (_Float16)x0.z; d[3] = (_Float16)x0.w;
                    d[4] = (_Float16)x1.x; d[5] = (_Float16)x1.y;
                    d[6] = (_Float16)x1.z; d[7] = (_Float16)x1.w;
                } else {
                    *(uint4*)d = *(const uint4*)((const __half*)X + (size_t)gr * 128 + c8 * 8);
                }
            } else {
                uint4 z; z.x = 0; z.y = 0; z.z = 0; z.w = 0;
                *(uint4*)d = z;
            }
        }
        __syncthreads();

        const int rowb = base + wv * 16;

        // A-fragments for this wave's 16 rows (4 x ds_read_b128)
        f16x8 af[4];
#pragma unroll
        for (int ks = 0; ks < 4; ks++)
            af[ks] = *(const f16x8*)&Xh[wv * 16 + m][ks * 32 + q * 8];

        f32x4 acc[8];
#pragma unroll
        for (int nt = 0; nt < 8; nt++) { acc[nt][0] = 0.f; acc[nt][1] = 0.f; acc[nt][2] = 0.f; acc[nt][3] = 0.f; }

        // stream B-fragments from LDS per nt (4 x ds_read_b128 + 4 MFMA)
#pragma unroll
        for (int nt = 0; nt < 8; nt++) {
            f16x8 b0v = *(const f16x8*)&Wf[nt][0][lane * 8];
            f16x8 b1v = *(const f16x8*)&Wf[nt][1][lane * 8];
            f16x8 b2v = *(const f16x8*)&Wf[nt][2][lane * 8];
            f16x8 b3v = *(const f16x8*)&Wf[nt][3][lane * 8];
            acc[nt] = __builtin_amdgcn_mfma_f32_16x16x32_f16(af[0], b0v, acc[nt], 0, 0, 0);
            acc[nt] = __builtin_amdgcn_mfma_f32_16x16x32_f16(af[1], b1v, acc[nt], 0, 0, 0);
            acc[nt] = __builtin_amdgcn_mfma_f32_16x16x32_f16(af[2], b2v, acc[nt], 0, 0, 0);
            acc[nt] = __builtin_amdgcn_mfma_f32_16x16x32_f16(af[3], b3v, acc[nt], 0, 0, 0);
        }

        // Y writes (fp16 scalar stores; C-layout)
#pragma unroll
        for (int nt = 0; nt < 8; nt++) {
#pragma unroll
            for (int i = 0; i < 4; i++) {
                int r = rowb + q * 4 + i;
                if (r < N) Y[(size_t)r * 128 + nt * 16 + m] = __float2half(acc[nt][i]);
            }
        }

        // fused attention dots: per-lane partials, butterfly over the 16 cols
        if (H == 4) {
            float ph[4][4], pdv[4][4];
#pragma unroll
            for (int h = 0; h < 4; h++)
#pragma unroll
                for (int i = 0; i < 4; i++) {
                    ph[h][i]  = acc[2 * h][i] * atts_v[2 * h] + acc[2 * h + 1][i] * atts_v[2 * h + 1];
                    pdv[h][i] = acc[2 * h][i] * attd_v[2 * h] + acc[2 * h + 1][i] * attd_v[2 * h + 1];
                }
#pragma unroll
            for (int lvl = 0; lvl < 4; lvl++) {
                const int msk = 1 << lvl;
#pragma unroll
                for (int h = 0; h < 4; h++)
#pragma unroll
                    for (int i = 0; i < 4; i++) {
                        ph[h][i]  += __shfl_xor(ph[h][i], msk, 64);
                        pdv[h][i] += __shfl_xor(pdv[h][i], msk, 64);
                    }
            }
            if (m == 0) {
#pragma unroll
                for (int i = 0; i < 4; i++) {
                    int r = rowb + q * 4 + i;
                    if (r < N) {
#pragma unroll
                        for (int h = 0; h < 4; h++) {
                            as_[(size_t)r * 4 + h] = ph[h][i];
                            ad_[(size_t)r * 4 + h] = pdv[h][i];
                        }
                    }
                }
            }
        } else {
            float ps[4], pdv[4];
#pragma unroll
            for (int i = 0; i < 4; i++) {
                float s = 0.f, dsum = 0.f;
#pragma unroll
                for (int nt = 0; nt < 8; nt++) {
                    s    += acc[nt][i] * atts_v[nt];
                    dsum += acc[nt][i] * attd_v[nt];
                }
                ps[i] = s; pdv[i] = dsum;
            }
#pragma unroll
            for (int lvl = 0; lvl < 4; lvl++) {
                const int msk = 1 << lvl;
#pragma unroll
                for (int i = 0; i < 4; i++) {
                    ps[i]  += __shfl_xor(ps[i], msk, 64);
                    pdv[i] += __shfl_xor(pdv[i], msk, 64);
                }
            }
            if (m == 0) {
#pragma unroll
                for (int i = 0; i < 4; i++) {
                    int r = rowb + q * 4 + i;
                    if (r < N) { as_[r] = ps[i]; ad_[r] = pdv[i]; }
                }
            }
        }
        __syncthreads();   // protect Xh before next tile's staging
    }
}

// ---------------- aggregation: one wave per dst node ----------------
// R11 gather core (measured 70.9-71.1us, stable): 16 lanes per edge at
// 16B/lane; batches of 16 edges, 4 uint4 loads issued before consumption;
// tail predicated by zero weight. Accumulator = 8 NAMED SCALARS (no array
// -> no alloca -> no PromoteAlloca-to-LDS; R14 lesson).
// R15 epilogue: wave-parallel. After the xor-16/32 butterfly all lanes hold
// the reduced sums; each lane finalizes 2 cols (sub*8+2g) via cndmask
// selection on SSA scalars -> half2/float2 store.

template <int H, typename TO>
__global__ __launch_bounds__(256) void k_agg(
    const __half* __restrict__ feat,  // [N,128] fp16
    const float* __restrict__ asrc,   // [N,H]
    const float* __restrict__ adst,   // [N,H]
    const int*   __restrict__ off,    // [N+1]
    const int*   __restrict__ esrc,   // [E]
    const float* __restrict__ bias,   // [128]
    TO*          __restrict__ out,    // [N,128]
    int N)
{
    __shared__ __attribute__((aligned(16))) int   sj[4][64];
    __shared__ __attribute__((aligned(16))) float sp[4][64 * H];  // head-major

    int wave = threadIdx.x >> 6;
    int lane = threadIdx.x & 63;
    int node = (blockIdx.x * 256 + threadIdx.x) >> 6;
    if (node >= N) return;
    int beg = off[node], end = off[node + 1];

    float adst_i[H];
#pragma unroll
    for (int h = 0; h < H; h++) adst_i[h] = adst[(size_t)node * H + h];

    const int g    = lane >> 4;                    // edge sub-slot 0..3
    const int sub  = lane & 15;                    // col octet: cols sub*8..+7
    const int head = (H == 4) ? (sub >> 2) : 0;    // 32 cols per head
    const __half* fb = feat + sub * 8;

    float o0 = 0.f, o1 = 0.f, o2 = 0.f, o3 = 0.f;
    float o4 = 0.f, o5 = 0.f, o6 = 0.f, o7 = 0.f;
    float ssum = 0.f;

    auto accum8 = [&](const __half* hp, float aa) {
        ssum += aa;
        o0 = fmaf(aa, __half2float(hp[0]), o0);
        o1 = fmaf(aa, __half2float(hp[1]), o1);
        o2 = fmaf(aa, __half2float(hp[2]), o2);
        o3 = fmaf(aa, __half2float(hp[3]), o3);
        o4 = fmaf(aa, __half2float(hp[4]), o4);
        o5 = fmaf(aa, __half2float(hp[5]), o5);
        o6 = fmaf(aa, __half2float(hp[6]), o6);
        o7 = fmaf(aa, __half2float(hp[7]), o7);
    };

    for (int cbeg = beg; cbeg < end; cbeg += 64) {
        int cnt = end - cbeg; if (cnt > 64) cnt = 64;
        if (lane < cnt) {
            int j = esrc[cbeg + lane];
            sj[wave][lane] = j;
            if (H == 4) {
                float4 av = *(const float4*)(asrc + (size_t)j * 4);
                float e;
                e = av.x + adst_i[0]; e = e > 0.f ? e : 0.2f * e; sp[wave][0 * 64 + lane] = __expf(e);
                e = av.y + adst_i[1]; e = e > 0.f ? e : 0.2f * e; sp[wave][1 * 64 + lane] = __expf(e);
                e = av.z + adst_i[2]; e = e > 0.f ? e : 0.2f * e; sp[wave][2 * 64 + lane] = __expf(e);
                e = av.w + adst_i[3]; e = e > 0.f ? e : 0.2f * e; sp[wave][3 * 64 + lane] = __expf(e);
            } else {
                float e = asrc[j] + adst_i[0];
                e = e > 0.f ? e : 0.2f * e;
                sp[wave][lane] = __expf(e);
            }
        }
        asm volatile("s_waitcnt lgkmcnt(0)" ::: "memory");

        // batches of 16 edges: issue 4 gathers back-to-back, then consume.
        for (int b0 = 0; b0 < cnt; b0 += 16) {
            float aa[4]; uint4 hv[4];
#pragma unroll
            for (int u = 0; u < 4; u++) {
                int e  = b0 + 4 * u + g;
                bool ok = e < cnt;
                int ec = ok ? e : 0;
                int j  = sj[wave][ec];
                aa[u]  = ok ? sp[wave][head * 64 + ec] : 0.f;
                hv[u]  = *(const uint4*)(fb + (size_t)j * 128);
            }
            accum8((const __half*)&hv[0], aa[0]);
            accum8((const __half*)&hv[1], aa[1]);
            accum8((const __half*)&hv[2], aa[2]);
            accum8((const __half*)&hv[3], aa[3]);
        }
        // same-wave lockstep: staging of the next chunk cannot race these reads
    }

    // reduce across the 4 edge-groups: butterfly leaves full sums in ALL lanes
    o0 += __shfl_xor(o0, 16, 64); o0 += __shfl_xor(o0, 32, 64);
    o1 += __shfl_xor(o1, 16, 64); o1 += __shfl_xor(o1, 32, 64);
    o2 += __shfl_xor(o2, 16, 64); o2 += __shfl_xor(o2, 32, 64);
    o3 += __shfl_xor(o3, 16, 64); o3 += __shfl_xor(o3, 32, 64);
    o4 += __shfl_xor(o4, 16, 64); o4 += __shfl_xor(o4, 32, 64);
    o5 += __shfl_xor(o5, 16, 64); o5 += __shfl_xor(o5, 32, 64);
    o6 += __shfl_xor(o6, 16, 64); o6 += __shfl_xor(o6, 32, 64);
    o7 += __shfl_xor(o7, 16, 64); o7 += __shfl_xor(o7, 32, 64);
    ssum += __shfl_xor(ssum, 16, 64);
    ssum += __shfl_xor(ssum, 32, 64);

    // wave-parallel epilogue: lane finalizes cols sub*8+2g, +1 (SSA selects)
    float so0 = o0, so1 = o1;
    so0 = (g == 1) ? o2 : so0;  so1 = (g == 1) ? o3 : so1;
    so0 = (g == 2) ? o4 : so0;  so1 = (g == 2) ? o5 : so1;
    so0 = (g == 3) ? o6 : so0;  so1 = (g == 3) ? o7 : so1;

    const int c2 = sub * 8 + 2 * g;
    float inv = 1.f / (ssum + 1e-16f);
    float r0 = so0 * inv + bias[c2];
    float r1 = so1 * inv + bias[c2 + 1];
    float e0 = __expf(r0) - 1.0f;                  // cheap ELU (abs err ~1e-6)
    float e1 = __expf(r1) - 1.0f;
    r0 = r0 > 0.f ? r0 : e0;
    r1 = r1 > 0.f ? r1 : e1;

    if constexpr (sizeof(TO) == 2) {
        *(__half2*)((__half*)out + (size_t)node * 128 + c2) = __floats2half2_rn(r0, r1);
    } else {
        *(float2*)((float*)out + (size_t)node * 128 + c2) = make_float2(r0, r1);
    }
}

// ---------------- launch ----------------

extern "C" void kernel_launch(void* const* d_in, const int* in_sizes, int n_in,
                              void* d_out, int out_size, void* d_ws, size_t ws_size,
                              hipStream_t stream)
{
    const float* x    = (const float*)d_in[0];
    const int*   a    = (const int*)  d_in[1];
    const float* W1   = (const float*)d_in[2];
    const float* as1w = (const float*)d_in[3];
    const float* ad1w = (const float*)d_in[4];
    const float* b1   = (const float*)d_in[5];
    const float* W2   = (const float*)d_in[6];
    const float* as2w = (const float*)d_in[7];
    const float* ad2w = (const float*)d_in[8];
    const float* b2   = (const float*)d_in[9];

    const int N = in_sizes[0] / 128;
    const int E = in_sizes[1] / 2;
    const int* srcA = a;
    const int* dstA = a + E;
    const int NBUCK = (N + 127) >> 7;

    char* ws = (char*)d_ws;
    size_t o = 0;
    auto alloc = [&](size_t bytes) -> void* {
        void* p = ws + o;
        o += (bytes + 255) & ~(size_t)255;
        return p;
    };
    __half* hbuf  = (__half*)alloc((size_t)N * 128 * 2);  // fp16 gather payload
    __half* hact  = (__half*)alloc((size_t)N * 128 * 2);  // elu(gat1) fp16, GEMM2 input
    float*  as1   = (float*) alloc((size_t)N * 4 * 4);
    float*  ad1   = (float*) alloc((size_t)N * 4 * 4);
    float*  as2   = (float*) alloc((size_t)N * 4);
    float*  ad2   = (float*) alloc((size_t)N * 4);
    int*    off   = (int*)   alloc((size_t)(N + 1) * 4);
    int*    esrc  = (int*)   alloc((size_t)E * 4);
    int*    tmp   = (int*)   alloc((size_t)E * 4);
    int*    bcnt  = (int*)   alloc(1024 * 4);
    int*    bbase = (int*)   alloc(1025 * 4);
    int*    bcur  = (int*)   alloc(1024 * 4);

    // CSR build (rebuilt each launch; ws is re-poisoned)
    hipMemsetAsync(bcnt, 0, (size_t)NBUCK * 4, stream);
    k_hist<<<256, 256, 0, stream>>>(dstA, bcnt, E, NBUCK);
    k_bscan<<<1, 1024, 0, stream>>>(bcnt, bbase, bcur, off, NBUCK, N, E);
    k_binscatter<<<(E + 8191) / 8192, 256, 0, stream>>>(srcA, dstA, bcur, tmp, E, NBUCK);
    k_bsort<<<NBUCK, 256, 0, stream>>>(tmp, bbase, off, esrc, N);

    // layer 1 (MFMA GEMM + fused attdot, fp16 Y)
    k_gemm_mfma<4, float><<<768, 256, 0, stream>>>(x, W1, as1w, ad1w, hbuf, as1, ad1, N);
    k_agg<4, __half><<<(N + 3) / 4, 256, 0, stream>>>(hbuf, as1, ad1, off, esrc, b1, hact, N);

    // layer 2
    k_gemm_mfma<1, __half><<<768, 256, 0, stream>>>(hact, W2, as2w, ad2w, hbuf, as2, ad2, N);
    k_agg<1, float><<<(N + 3) / 4, 256, 0, stream>>>(hbuf, as2, ad2, off, esrc, b2, (float*)d_out, N);
}